// Round 17
// baseline (273.341 us; speedup 1.0000x reference)
//
#include <hip/hip_runtime.h>
#include <hip/hip_bf16.h>
#include <hip/hip_fp16.h>
#include <cstdint>
#include <cstddef>

#define BB 32
#define NN 256
#define MM 256
#define DD 512
#define NEGF (-1e9f)
#define LOG2E 1.4426950408889634f
#define SKWN 196608  // 384 planes * 512 floats (AoS th0,th1,a0,a1 per lane)
#define QPN  98304   // 384 planes * 256 dwords (2 q-words per lane)
#define EPN  98304   // 384 planes * 256 floats (2 E per lane)

typedef __fp16 h2 __attribute__((ext_vector_type(2)));
typedef float f32x4_t __attribute__((ext_vector_type(4)));
typedef unsigned int u32x4_t __attribute__((ext_vector_type(4)));
typedef short s16x8 __attribute__((ext_vector_type(8)));

__device__ __forceinline__ uint32_t pack_q(float a, float b) {
  h2 r = __builtin_amdgcn_cvt_pkrtz(a, b);
  return __builtin_bit_cast(uint32_t, r);
}
__device__ __forceinline__ float2 unpack_q(uint32_t u) {
  h2 r = __builtin_bit_cast(h2, u);
  return make_float2((float)r.x, (float)r.y);
}
__device__ __forceinline__ float softplus_f(float x) {
  return fmaxf(x, 0.f) + __logf(1.f + __expf(-fabsf(x)));
}
__device__ __forceinline__ float logsig_f(float x) {
  return fminf(x, 0.f) - __logf(1.f + __expf(-fabsf(x)));
}
__device__ __forceinline__ short f2bf(float f) {
  uint32_t u = __builtin_bit_cast(uint32_t, f);
  u += 0x7FFFu + ((u >> 16) & 1u);
  return (short)(u >> 16);
}

#define WAITV(N) do { \
  asm volatile("s_waitcnt vmcnt(" #N ")" ::: "memory"); \
  __builtin_amdgcn_sched_barrier(0); \
} while (0)

#define DRAIN() do { \
  asm volatile("s_waitcnt vmcnt(0) lgkmcnt(0)" ::: "memory"); \
  __builtin_amdgcn_sched_barrier(0); \
} while (0)

// raw step barrier: lgkm fence (publish 1-dword ds_write) + s_barrier.
// NOT __syncthreads (that drains vmcnt(0) and kills the staging pipeline).
#define STEPBAR() do { \
  asm volatile("s_waitcnt lgkmcnt(0)" ::: "memory"); \
  __builtin_amdgcn_sched_barrier(0); \
  __builtin_amdgcn_s_barrier(); \
  asm volatile("" ::: "memory"); \
} while (0)

// ---------- bf16-MFMA GEMM + activation + skew AoS side store --------------
__global__ __launch_bounds__(256) void gemm_mfma(const float* __restrict__ ZX,
                                                 const float* __restrict__ ZY,
                                                 const float* __restrict__ GX,
                                                 const float* __restrict__ GY,
                                                 float* __restrict__ theta,
                                                 float* __restrict__ Amat,
                                                 float* __restrict__ skw) {
  const int z  = blockIdx.z;
  const int b  = z & 31;
  const int op = z >> 5;
  const int ty = blockIdx.y;
  const int tx = blockIdx.x;
  const float* Xb = (op ? GX : ZX) + (size_t)b * NN * DD;
  const float* Yb = (op ? GY : ZY) + (size_t)b * MM * DD;
  float* outb = (op ? Amat : theta) + (size_t)b * NN * MM;
  float* skb  = skw + (size_t)b * SKWN;

  __shared__ short xs[64][40];
  __shared__ short ys[64][40];

  const int tid = threadIdx.x;
  const int l   = tid & 63;
  const int w   = tid >> 6;
  const int r0  = (w >> 1) * 32;
  const int c0  = (w & 1) * 32;
  const int srow = tid >> 2;
  const int scg  = (tid & 3) * 8;

  f32x4_t acc[2][2];
  #pragma unroll
  for (int i = 0; i < 2; ++i)
    #pragma unroll
    for (int j = 0; j < 2; ++j) acc[i][j] = f32x4_t{0.f, 0.f, 0.f, 0.f};

  const int lr = l & 15;
  const int kof = (l >> 4) * 8;

  for (int ks = 0; ks < 16; ++ks) {
    const int k0 = ks * 32;
    const float4 xv0 = *(const float4*)(Xb + (size_t)(ty * 64 + srow) * DD + k0 + scg);
    const float4 xv1 = *(const float4*)(Xb + (size_t)(ty * 64 + srow) * DD + k0 + scg + 4);
    const float4 yv0 = *(const float4*)(Yb + (size_t)(tx * 64 + srow) * DD + k0 + scg);
    const float4 yv1 = *(const float4*)(Yb + (size_t)(tx * 64 + srow) * DD + k0 + scg + 4);
    __syncthreads();
    s16x8 xp, yp;
    xp[0] = f2bf(xv0.x); xp[1] = f2bf(xv0.y); xp[2] = f2bf(xv0.z); xp[3] = f2bf(xv0.w);
    xp[4] = f2bf(xv1.x); xp[5] = f2bf(xv1.y); xp[6] = f2bf(xv1.z); xp[7] = f2bf(xv1.w);
    yp[0] = f2bf(yv0.x); yp[1] = f2bf(yv0.y); yp[2] = f2bf(yv0.z); yp[3] = f2bf(yv0.w);
    yp[4] = f2bf(yv1.x); yp[5] = f2bf(yv1.y); yp[6] = f2bf(yv1.z); yp[7] = f2bf(yv1.w);
    *(s16x8*)&xs[srow][scg] = xp;
    *(s16x8*)&ys[srow][scg] = yp;
    __syncthreads();
    const s16x8 a0 = *(const s16x8*)&xs[r0 + lr][kof];
    const s16x8 a1 = *(const s16x8*)&xs[r0 + 16 + lr][kof];
    const s16x8 b0 = *(const s16x8*)&ys[c0 + lr][kof];
    const s16x8 b1 = *(const s16x8*)&ys[c0 + 16 + lr][kof];
    acc[0][0] = __builtin_amdgcn_mfma_f32_16x16x32_bf16(a0, b0, acc[0][0], 0, 0, 0);
    acc[0][1] = __builtin_amdgcn_mfma_f32_16x16x32_bf16(a0, b1, acc[0][1], 0, 0, 0);
    acc[1][0] = __builtin_amdgcn_mfma_f32_16x16x32_bf16(a1, b0, acc[1][0], 0, 0, 0);
    acc[1][1] = __builtin_amdgcn_mfma_f32_16x16x32_bf16(a1, b1, acc[1][1], 0, 0, 0);
  }

  #pragma unroll
  for (int i = 0; i < 2; ++i) {
    #pragma unroll
    for (int j = 0; j < 2; ++j) {
      #pragma unroll
      for (int r = 0; r < 4; ++r) {
        const int R = ty * 64 + r0 + i * 16 + (l >> 4) * 4 + r;
        const int C = tx * 64 + c0 + j * 16 + (l & 15);
        const float v = acc[i][j][r];
        const float act = (op == 0) ? softplus_f(v) : logsig_f(v);
        outb[(size_t)R * MM + C] = act;
        const int m = (C + 1) + (R >> 1);          // plane, 1..383
        skb[(size_t)m * 512 + ((R >> 1) << 2) + (op ? 2 : 0) + (R & 1)] =
            act * LOG2E;                            // base-2 domain
      }
    }
  }
}

// -------- soft-NW: 2 waves/batch, 2 rows/lane, skewed, LDS-staged ----------
// 128 threads; global lane t owns grid rows 2t+1, 2t+2; fwd step m: col
// j = m - t (planes 1..383). Cross-wave boundary (1-2 dwords/step) via
// 3-slot rotating LDS buffer + raw s_barrier per step. Staging is per-wave
// private (each wave loads/consumes its own half-plane) so counted vmcnt
// stays per-wave sound. E stored coalesced per plane; untwist separate.
__global__ __launch_bounds__(128, 1) void nw_wave(const float* __restrict__ skwA,
                                                  uint32_t* __restrict__ qSA,
                                                  float* __restrict__ eSA) {
  const int b = blockIdx.x;
  const int t = threadIdx.x;        // 0..127
  const int w64 = (t >> 6) << 6;    // 0 or 64
  const float* skw = skwA + (size_t)b * SKWN;
  uint32_t* qS = qSA + (size_t)b * QPN;
  float* eSb = eSA + (size_t)b * EPN;

  __shared__ f32x4_t stg[12][128];   // fwd: 3 banks x 4 planes (AoS 16B/lane)
  __shared__ uint32_t qstg[12][256]; // bwd: 3 banks x 4 planes (2 dw/lane)
  __shared__ float xv[3];            // fwd boundary V (w0l63 -> w1l0)
  __shared__ float xe[3];            // bwd boundary E (w1l0 -> w0l63)
  __shared__ uint32_t xq[3];         // bwd boundary Q word

  if (t < 3) { xv[t] = NEGF; xe[t] = 0.f; xq[t] = 0u; }
  __syncthreads();   // once, before pipelines

  // ================= forward =================
  float vp[2] = {NEGF, NEGF};
  float vu_sh = NEGF, vd_sh = NEGF;

  auto fstage = [&](int rbase, int mlo) {
    #pragma unroll
    for (int q = 0; q < 4; ++q) {
      int m = mlo + q; m = m < 1 ? 1 : (m > 383 ? 383 : m);
      __builtin_amdgcn_global_load_lds((const void*)(skw + (size_t)m * 512 + 4 * t),
                                       (void*)&stg[rbase + q][w64], 16, 0, 0);
    }
  };

  fstage(0, 1); fstage(4, 5); fstage(8, 9);
  for (int h = 0; h < 96; ++h) {
    const int m0 = 1 + 4 * h;
    const int R = (h % 3) * 4;
    if (h == 0)      WAITV(8);
    else if (h == 1) WAITV(12);
    else             WAITV(16);
    f32x4_t c4 = stg[R][t];
    f32x4_t n4;
    #pragma unroll
    for (int u = 0; u < 4; ++u) {
      if (u < 3) n4 = stg[R + u + 1][t];
      const int m = m0 + u;
      const float xvr1 = xv[(m + 2) % 3];   // slot m-1
      const float xvr2 = xv[(m + 1) % 3];   // slot m-2
      __builtin_amdgcn_sched_barrier(0);
      const int j = m - t;
      const bool actv = (j >= 1) && (j <= 256);
      float vu_in = (t == 64) ? xvr1 : vu_sh;
      float vd_in = (t == 64) ? xvr2 : vd_sh;
      if (t == 0) { vu_in = NEGF; vd_in = (m == 1) ? 0.f : NEGF; }
      float vn[2];
      uint32_t pk[2];
      #pragma unroll
      for (int k = 0; k < 2; ++k) {
        const float vu  = (k == 0) ? vu_in : vn[0];
        const float vdk = (k == 0) ? vd_in : vp[0];
        const float vl  = vp[k];
        const float a  = c4[2 + k];
        const float th = c4[k];
        const float x0 = a + vu;
        const float x2 = a + vl;
        const float mx = fmaxf(fmaxf(x0, vdk), x2);
        const float e0 = __builtin_amdgcn_exp2f(x0 - mx);
        const float e1 = __builtin_amdgcn_exp2f(vdk - mx);
        const float e2 = __builtin_amdgcn_exp2f(x2 - mx);
        const float Z  = e0 + e1 + e2;
        const float rz = __builtin_amdgcn_rcpf(Z);
        const float v  = th + mx + __builtin_amdgcn_logf(Z);  // log2
        vn[k] = actv ? v : vp[k];
        pk[k] = pack_q(e0 * rz, e2 * rz);   // (q1,q3); q2 = 1-q1-q3
      }
      const float nsh = __shfl_up(vn[1], 1);
      const int ms = (m <= 383) ? m : 0;
      *(uint2*)(qS + (size_t)ms * 256 + 2 * t) = make_uint2(pk[0], pk[1]);
      if (t == 63) xv[m % 3] = vn[1];
      vd_sh = vu_sh; vu_sh = nsh;
      vp[0] = vn[0]; vp[1] = vn[1];
      if (u < 3) c4 = n4;
      STEPBAR();
    }
    fstage(R, m0 + 12);
  }

  DRAIN();  // own qS stores retired before own bwd staging reads them
  __builtin_amdgcn_s_barrier();

  // ================= backward =================
  float ep[2] = {0.f, 0.f};
  float sh_e1 = 0.f, sh_e2 = 0.f;
  uint32_t sh_q1 = 0u, sh_q2 = 0u;
  uint32_t qm1[2] = {0u, 0u};

  auto qstage = [&](int rbase, int Phi) {
    #pragma unroll
    for (int q = 0; q < 4; ++q) {
      int P = Phi - q; P = P < 0 ? 0 : (P > 383 ? 383 : P);
      const uint32_t* s0 = qS + (size_t)P * 256 + ((t >> 6) << 7) + (t & 63);
      __builtin_amdgcn_global_load_lds((const void*)s0,
                                       (void*)&qstg[rbase + q][(t >> 6) << 7], 4, 0, 0);
      __builtin_amdgcn_global_load_lds((const void*)(s0 + 64),
                                       (void*)&qstg[rbase + q][((t >> 6) << 7) + 64], 4, 0, 0);
    }
  };

  qstage(0, 383); qstage(4, 379); qstage(8, 375);
  for (int n = 0; n < 96; ++n) {
    const int R = (n % 3) * 4;
    if (n == 0)      WAITV(16);
    else if (n == 1) WAITV(20);
    else             WAITV(24);
    uint2 cur = *(uint2*)&qstg[R][2 * t];
    uint2 nxt;
    #pragma unroll
    for (int u = 0; u < 4; ++u) {
      if (u < 3) nxt = *(uint2*)&qstg[R + u + 1][2 * t];
      const int mp = 4 * n + u;
      const int P  = 383 - mp;
      const float    xer1 = xe[(mp + 2) % 3];   // slot mp-1
      const float    xer2 = xe[(mp + 1) % 3];   // slot mp-2
      const uint32_t xqr1 = xq[(mp + 2) % 3];
      const uint32_t xqr2 = xq[(mp + 1) % 3];
      __builtin_amdgcn_sched_barrier(0);
      const int j = P - t;
      const bool actv = (j >= 1) && (j <= 256);
      const bool jok  = (j <= 255);
      const float se1 = (t == 63) ? xer1 : sh_e1;
      const float se2 = (t == 63) ? xer2 : sh_e2;
      uint32_t sq1 = (t == 63) ? xqr1 : sh_q1;
      uint32_t sq2 = (t == 63) ? xqr2 : sh_q2;
      sq1 = (t == 127) ? 0u : sq1;
      sq2 = (t == 127 || !jok) ? 0x3C00u : sq2;
      const uint32_t qm0v = jok ? qm1[0] : 0x3C00u;
      const uint32_t qm1v = jok ? qm1[1] : 0x3C00u;
      float en[2];
      // k = 1 first (row 2t+2), then k = 0 (needs en[1])
      {
        const float2 fA = unpack_q(sq1);    // Q1 of (2t+3, j)
        const float2 fB = unpack_q(sq2);    // Q of (2t+3, j+1)
        const float2 fC = unpack_q(qm1v);   // Q3 of (2t+2, j+1)
        float E = fA.x * se1 + (1.f - fB.x - fB.y) * se2 + fC.y * ep[1];
        if (n == 0 && u == 0) E = (t == 127) ? 1.f : E;  // seed (256,256)
        en[1] = actv ? E : 0.f;
      }
      {
        const float2 fA = unpack_q(cur.y);  // Q1 of (2t+2, j), same plane
        const float2 fB = unpack_q(qm1v);   // Q of (2t+2, j+1)
        const float2 fC = unpack_q(qm0v);   // Q3 of (2t+1, j+1)
        const float E = fA.x * en[1] + (1.f - fB.x - fB.y) * ep[1] + fC.y * ep[0];
        en[0] = actv ? E : 0.f;
      }
      const float ne = __shfl_down(en[0], 1);
      const uint32_t nq = (uint32_t)__shfl_down((int)cur.x, 1);
      *(float2*)(eSb + (size_t)mp * 256 + 2 * t) = make_float2(en[0], en[1]);
      if (t == 64) { xe[mp % 3] = en[0]; xq[mp % 3] = cur.x; }
      sh_e2 = sh_e1; sh_e1 = ne;
      sh_q2 = sh_q1; sh_q1 = nq;
      ep[0] = en[0]; ep[1] = en[1];
      qm1[0] = cur.x; qm1[1] = cur.y;
      if (u < 3) cur = nxt;
      STEPBAR();
    }
    qstage(R, 371 - 4 * n);
  }
}

// -------- skew-layout E -> row-major aln: aln[r][c] = eS[382-c-(r>>1)][r] --
__global__ __launch_bounds__(256) void untwist(const float* __restrict__ eS,
                                               float* __restrict__ aln) {
  const int b  = blockIdx.z;
  const int r0 = blockIdx.y * 64;
  const int c0 = blockIdx.x * 64;
  const int tid = threadIdx.x;
  const float* ep = eS + (size_t)b * EPN;

  __shared__ float ld[95][65];

  const int lx = tid & 63;
  const int wy = tid >> 6;
  const int mbase = 288 - c0 - (r0 >> 1);
  #pragma unroll
  for (int k = 0; k < 24; ++k) {
    const int p = wy + 4 * k;
    if (p < 95) ld[p][lx] = ep[(size_t)(mbase + p) * 256 + r0 + lx];
  }
  __syncthreads();
  #pragma unroll
  for (int k = 0; k < 16; ++k) {
    const int rr = wy + 4 * k;
    aln[(size_t)b * NN * MM + (size_t)(r0 + rr) * MM + c0 + lx] =
        ld[94 - lx - (rr >> 1)][rr];
  }
}

// ---------------- launcher ----------------
extern "C" void kernel_launch(void* const* d_in, const int* in_sizes, int n_in,
                              void* d_out, int out_size, void* d_ws, size_t ws_size,
                              hipStream_t stream) {
  const float* zx = (const float*)d_in[0];
  const float* zy = (const float*)d_in[1];
  const float* gx = (const float*)d_in[2];
  const float* gy = (const float*)d_in[3];

  float* out   = (float*)d_out;
  float* aln   = out;                              // [B][N][M]
  float* theta = out + (size_t)BB * NN * MM;       // [B][N][M]
  float* Amat  = out + (size_t)2 * BB * NN * MM;   // [B][N][M]

  float* ws  = (float*)d_ws;
  float* skw = ws;                                       // [B][384][512] f32
  uint32_t* qS = (uint32_t*)(ws + (size_t)BB * SKWN);    // [B][384][256] u32
  float* eS = ws + (size_t)BB * SKWN + (size_t)BB * QPN; // [B][384][256] f32

  gemm_mfma<<<dim3(4, 4, 64), 256, 0, stream>>>(zx, zy, gx, gy,
                                                theta, Amat, skw);
  nw_wave<<<BB, 128, 0, stream>>>(skw, qS, eS);
  untwist<<<dim3(4, 4, BB), 256, 0, stream>>>(eS, aln);
}

// Round 19
// 161.322 us; speedup vs baseline: 1.6944x; 1.6944x over previous
//
#include <hip/hip_runtime.h>
#include <hip/hip_bf16.h>
#include <hip/hip_fp16.h>
#include <cstdint>
#include <cstddef>
#include <type_traits>

#define BB 32
#define NN 256
#define MM 256
#define DD 512
#define NEGF (-1e9f)
#define LOG2E 1.4426950408889634f
#define SPLN 82176   // 321*256 floats: th/a skew planes per batch
#define QPLN 82176   // 321*64 u32x4 in 4B words per batch
#define EPLN 81920   // 320*256 floats: E skew planes per batch

typedef __fp16 h2 __attribute__((ext_vector_type(2)));
typedef float f32x4_t __attribute__((ext_vector_type(4)));
typedef unsigned int u32x4_t __attribute__((ext_vector_type(4)));
typedef short s16x8 __attribute__((ext_vector_type(8)));

__device__ __forceinline__ uint32_t pack_q(float a, float b) {
  h2 r = __builtin_amdgcn_cvt_pkrtz(a, b);
  return __builtin_bit_cast(uint32_t, r);
}
__device__ __forceinline__ float2 unpack_q(uint32_t u) {
  h2 r = __builtin_bit_cast(h2, u);
  return make_float2((float)r.x, (float)r.y);
}
__device__ __forceinline__ float softplus_f(float x) {
  return fmaxf(x, 0.f) + __logf(1.f + __expf(-fabsf(x)));
}
__device__ __forceinline__ float logsig_f(float x) {
  return fminf(x, 0.f) - __logf(1.f + __expf(-fabsf(x)));
}
__device__ __forceinline__ short f2bf(float f) {   // RNE f32 -> bf16 bits
  uint32_t u = __builtin_bit_cast(uint32_t, f);
  u += 0x7FFFu + ((u >> 16) & 1u);
  return (short)(u >> 16);
}

#define WAITV(N) do { \
  asm volatile("s_waitcnt vmcnt(" #N ")" ::: "memory"); \
  __builtin_amdgcn_sched_barrier(0); \
} while (0)

#define DRAIN() do { \
  asm volatile("s_waitcnt vmcnt(0) lgkmcnt(0)" ::: "memory"); \
  __builtin_amdgcn_sched_barrier(0); \
} while (0)

#define SBAR() __builtin_amdgcn_sched_barrier(0)

// ---------- bf16-MFMA GEMM + activation + skew side store (both ops) -------
__global__ __launch_bounds__(256) void gemm_mfma(const float* __restrict__ ZX,
                                                 const float* __restrict__ ZY,
                                                 const float* __restrict__ GX,
                                                 const float* __restrict__ GY,
                                                 float* __restrict__ theta,
                                                 float* __restrict__ Amat,
                                                 float* __restrict__ thS,
                                                 float* __restrict__ aS) {
  const int z  = blockIdx.z;
  const int b  = z & 31;
  const int op = z >> 5;
  const int ty = blockIdx.y;
  const int tx = blockIdx.x;
  const float* Xb = (op ? GX : ZX) + (size_t)b * NN * DD;
  const float* Yb = (op ? GY : ZY) + (size_t)b * MM * DD;
  float* outb = (op ? Amat : theta) + (size_t)b * NN * MM;
  float* skb  = (op ? aS : thS) + (size_t)b * SPLN;

  __shared__ short xs[64][40];
  __shared__ short ys[64][40];

  const int tid = threadIdx.x;
  const int l   = tid & 63;
  const int w   = tid >> 6;
  const int r0  = (w >> 1) * 32;
  const int c0  = (w & 1) * 32;
  const int srow = tid >> 2;
  const int scg  = (tid & 3) * 8;

  f32x4_t acc[2][2];
  #pragma unroll
  for (int i = 0; i < 2; ++i)
    #pragma unroll
    for (int j = 0; j < 2; ++j) acc[i][j] = f32x4_t{0.f, 0.f, 0.f, 0.f};

  const int lr = l & 15;
  const int kof = (l >> 4) * 8;

  for (int ks = 0; ks < 16; ++ks) {
    const int k0 = ks * 32;
    const float4 xv0 = *(const float4*)(Xb + (size_t)(ty * 64 + srow) * DD + k0 + scg);
    const float4 xv1 = *(const float4*)(Xb + (size_t)(ty * 64 + srow) * DD + k0 + scg + 4);
    const float4 yv0 = *(const float4*)(Yb + (size_t)(tx * 64 + srow) * DD + k0 + scg);
    const float4 yv1 = *(const float4*)(Yb + (size_t)(tx * 64 + srow) * DD + k0 + scg + 4);
    __syncthreads();
    s16x8 xp, yp;
    xp[0] = f2bf(xv0.x); xp[1] = f2bf(xv0.y); xp[2] = f2bf(xv0.z); xp[3] = f2bf(xv0.w);
    xp[4] = f2bf(xv1.x); xp[5] = f2bf(xv1.y); xp[6] = f2bf(xv1.z); xp[7] = f2bf(xv1.w);
    yp[0] = f2bf(yv0.x); yp[1] = f2bf(yv0.y); yp[2] = f2bf(yv0.z); yp[3] = f2bf(yv0.w);
    yp[4] = f2bf(yv1.x); yp[5] = f2bf(yv1.y); yp[6] = f2bf(yv1.z); yp[7] = f2bf(yv1.w);
    *(s16x8*)&xs[srow][scg] = xp;
    *(s16x8*)&ys[srow][scg] = yp;
    __syncthreads();
    const s16x8 a0 = *(const s16x8*)&xs[r0 + lr][kof];
    const s16x8 a1 = *(const s16x8*)&xs[r0 + 16 + lr][kof];
    const s16x8 b0 = *(const s16x8*)&ys[c0 + lr][kof];
    const s16x8 b1 = *(const s16x8*)&ys[c0 + 16 + lr][kof];
    acc[0][0] = __builtin_amdgcn_mfma_f32_16x16x32_bf16(a0, b0, acc[0][0], 0, 0, 0);
    acc[0][1] = __builtin_amdgcn_mfma_f32_16x16x32_bf16(a0, b1, acc[0][1], 0, 0, 0);
    acc[1][0] = __builtin_amdgcn_mfma_f32_16x16x32_bf16(a1, b0, acc[1][0], 0, 0, 0);
    acc[1][1] = __builtin_amdgcn_mfma_f32_16x16x32_bf16(a1, b1, acc[1][1], 0, 0, 0);
  }

  #pragma unroll
  for (int i = 0; i < 2; ++i) {
    #pragma unroll
    for (int j = 0; j < 2; ++j) {
      const int Rb = ty * 64 + r0 + i * 16 + (l >> 4) * 4;  // base row, Rb%4==0
      const int C  = tx * 64 + c0 + j * 16 + (l & 15);
      float4 av;
      #pragma unroll
      for (int r = 0; r < 4; ++r) {
        const float v = acc[i][j][r];
        ((float*)&av)[r] = (op == 0) ? softplus_f(v) : logsig_f(v);
      }
      #pragma unroll
      for (int r = 0; r < 4; ++r)
        outb[(size_t)(Rb + r) * MM + C] = ((float*)&av)[r];
      // skew plane invariant over r (Rb%4==0); slots Rb..Rb+3 contiguous
      float4 sv;
      #pragma unroll
      for (int r = 0; r < 4; ++r) ((float*)&sv)[r] = ((float*)&av)[r] * LOG2E;
      *(float4*)&skb[(size_t)(C + 1 + (Rb >> 2)) * 256 + Rb] = sv;
    }
  }
}

// -------- wave-synchronous soft-NW, skewed, DS-pipelined, region-split -----
// One wave per batch; lane t owns grid rows 4t+1..4t+4, col j = m - t.
// Step bodies templated on FULL (all 64 lanes active): fwd m in [65,256],
// bwd mp in [64,255] skip all masking VALU.
__global__ __launch_bounds__(64, 1) void nw_wave(const float* __restrict__ thSA,
                                                 const float* __restrict__ aSA,
                                                 u32x4_t* __restrict__ qSA,
                                                 float* __restrict__ eSA) {
  const int b = blockIdx.x;
  const int t = threadIdx.x;
  const float* thS = thSA + (size_t)b * SPLN;
  const float* aS  = aSA  + (size_t)b * SPLN;
  u32x4_t* qS = qSA + (size_t)b * (QPLN / 4);
  float* eSb = eSA + (size_t)b * EPLN;

  __shared__ f32x4_t stg[24][64];

  // ================= forward =================
  float vp[4];
  #pragma unroll
  for (int k = 0; k < 4; ++k) vp[k] = NEGF;
  float vu_sh = NEGF, vd_sh = NEGF;

  auto fstage = [&](int rbase, int mlo) {
    #pragma unroll
    for (int q = 0; q < 4; ++q) {
      int m = mlo + q; m = m < 1 ? 1 : (m > 320 ? 320 : m);
      __builtin_amdgcn_global_load_lds((const void*)(thS + (size_t)m * 256 + 4 * t),
                                       (void*)&stg[rbase + q][0], 16, 0, 0);
      __builtin_amdgcn_global_load_lds((const void*)(aS + (size_t)m * 256 + 4 * t),
                                       (void*)&stg[rbase + 4 + q][0], 16, 0, 0);
    }
  };

  fstage(0, 1); fstage(8, 5); fstage(16, 9);
  u32x4_t* qpt = qS + 64 + t;   // plane m=1

  auto fwd_seg = [&](const int h, const auto fullc) {
    constexpr bool FULL = decltype(fullc)::value;
    const int m0 = 1 + 4 * h;
    const int R = (h % 3) * 8;
    if (h == 0)      WAITV(16);
    else if (h == 1) WAITV(20);
    else             WAITV(24);
    f32x4_t thc = stg[R][t], ac = stg[R + 4][t];
    f32x4_t thn, an;
    #pragma unroll
    for (int u = 0; u < 4; ++u) {
      if (u < 3) { thn = stg[R + u + 1][t]; an = stg[R + 4 + u + 1][t]; }
      SBAR();
      const int m = m0 + u;
      float vu_in = vu_sh, vd_in = vd_sh;
      if (t == 0) { vu_in = NEGF; vd_in = (m == 1) ? 0.f : NEGF; }
      bool actv = true;
      if constexpr (!FULL) {
        const int j = m - t;
        actv = (j >= 1) && (j <= 256);
      }
      float vn[4], e0v[4], e2v[4], rzv[4];
      #pragma unroll
      for (int k = 0; k < 4; ++k) {
        const float vu  = (k == 0) ? vu_in : vn[k - 1];
        const float vdk = (k == 0) ? vd_in : vp[k - 1];
        const float x0 = ac[k] + vu;
        const float x2 = ac[k] + vp[k];
        const float mx = fmaxf(fmaxf(x0, vdk), x2);   // v_max3
        const float e0 = __builtin_amdgcn_exp2f(x0 - mx);
        const float e1 = __builtin_amdgcn_exp2f(vdk - mx);
        const float e2 = __builtin_amdgcn_exp2f(x2 - mx);
        const float Z  = e0 + e1 + e2;
        rzv[k] = __builtin_amdgcn_rcpf(Z);
        const float v  = thc[k] + mx + __builtin_amdgcn_logf(Z);  // log2
        vn[k] = FULL ? v : (actv ? v : vp[k]);
        e0v[k] = e0; e2v[k] = e2;
      }
      const float nsh = __shfl_up(vn[3], 1);
      uint32_t pk[4];
      #pragma unroll
      for (int k = 0; k < 4; ++k)
        pk[k] = pack_q(e0v[k] * rzv[k], e2v[k] * rzv[k]);  // (q1,q3)
      qpt[0] = u32x4_t{pk[0], pk[1], pk[2], pk[3]};
      qpt += 64;
      vd_sh = vu_sh; vu_sh = nsh;
      #pragma unroll
      for (int k = 0; k < 4; ++k) vp[k] = vn[k];
      if (u < 3) { thc = thn; ac = an; }
    }
    fstage(R, m0 + 12);
  };

  for (int h = 0; h < 16; ++h)  fwd_seg(h, std::integral_constant<bool, false>{});
  for (int h = 16; h < 64; ++h) fwd_seg(h, std::integral_constant<bool, true>{});
  for (int h = 64; h < 80; ++h) fwd_seg(h, std::integral_constant<bool, false>{});

  DRAIN();  // qS RAW boundary (fwd stores -> bwd staged reads)

  // ================= backward =================
  float ep[4] = {0.f, 0.f, 0.f, 0.f};
  float sh_e1 = 0.f, sh_e2 = 0.f;
  uint32_t sh_q1 = 0u, sh_q2 = 0u;
  u32x4_t qm1 = u32x4_t{0u, 0u, 0u, 0u};
  const u32x4_t QONE = u32x4_t{0x3C00u, 0x3C00u, 0x3C00u, 0x3C00u};

  // round-14 form: one 16B DMA per plane (4 loads/segment) — proven layout.
  auto bstage = [&](int rbase, int Phi) {
    #pragma unroll
    for (int u = 0; u < 4; ++u) {
      int P = Phi - u; P = P < 0 ? 0 : (P > 320 ? 320 : P);
      __builtin_amdgcn_global_load_lds((const void*)(qS + (size_t)P * 64 + t),
                                       (void*)&stg[rbase + u][0], 16, 0, 0);
    }
  };

  bstage(0, 319); bstage(4, 315); bstage(8, 311);

  auto bwd_seg = [&](const int n, const auto fullc) {
    constexpr bool FULL = decltype(fullc)::value;
    const int R = (n % 3) * 4;
    if (n == 0)      WAITV(8);
    else if (n == 1) WAITV(12);
    else             WAITV(16);
    u32x4_t cur = __builtin_bit_cast(u32x4_t, stg[R][t]);
    u32x4_t nxt;
    #pragma unroll
    for (int u = 0; u < 4; ++u) {
      if (u < 3) nxt = __builtin_bit_cast(u32x4_t, stg[R + u + 1][t]);
      SBAR();
      const int mp = 4 * n + u;
      const int P  = 319 - mp;
      bool actv = true, jok = true;
      if constexpr (!FULL) {
        const int j = P - t;
        actv = (j >= 1) && (j <= 256);
        jok  = (j <= 255);
      }
      const u32x4_t qmm = FULL ? qm1 : (jok ? qm1 : QONE);
      const uint32_t sq1 = (t == 63) ? 0u : sh_q1;
      const uint32_t sq2 = (t == 63 || !jok) ? 0x3C00u : sh_q2;
      float en[4];
      #pragma unroll
      for (int kk = 0; kk < 4; ++kk) {
        const int k = 3 - kk;
        const uint32_t uA = (k < 3) ? cur[k + 1] : sq1;   // Q1 of (i+1, j)
        const uint32_t uB = (k < 3) ? qmm[k + 1] : sq2;   // Q of (i+1, j+1)
        const uint32_t uC = qmm[k];                       // Q3 of (i, j+1)
        const float2 fA = unpack_q(uA);
        const float2 fB = unpack_q(uB);
        const float2 fC = unpack_q(uC);
        const float q1u = fA.x;
        const float q2d = 1.f - fB.x - fB.y;
        const float q3l = fC.y;
        const float eu = (k < 3) ? en[k + 1] : sh_e1;
        const float ed = (k < 3) ? ep[k + 1] : sh_e2;
        const float el = ep[k];
        float E = q1u * eu + q2d * ed + q3l * el;
        if constexpr (!FULL) {
          if (n == 0 && u == 0 && k == 3) E = (t == 63) ? 1.f : E;  // seed
        }
        en[k] = FULL ? E : (actv ? E : 0.f);
      }
      const float ne = __shfl_down(en[0], 1);
      const uint32_t nq = (uint32_t)__shfl_down((int)cur[0], 1);
      *(f32x4_t*)(eSb + (size_t)mp * 256 + 4 * t) = f32x4_t{en[0], en[1], en[2], en[3]};
      sh_e2 = sh_e1; sh_e1 = ne;
      sh_q2 = sh_q1; sh_q1 = nq;
      ep[0] = en[0]; ep[1] = en[1]; ep[2] = en[2]; ep[3] = en[3];
      qm1 = cur;
      if (u < 3) cur = nxt;
    }
    bstage(R, 307 - 4 * n);
  };

  for (int n = 0; n < 16; ++n)  bwd_seg(n, std::integral_constant<bool, false>{});
  for (int n = 16; n < 64; ++n) bwd_seg(n, std::integral_constant<bool, true>{});
  for (int n = 64; n < 80; ++n) bwd_seg(n, std::integral_constant<bool, false>{});
}

// -------- skew-layout E -> row-major aln (tiled LDS transpose) --------
__global__ __launch_bounds__(256) void untwist(const float* __restrict__ eS,
                                               float* __restrict__ aln) {
  const int b  = blockIdx.z;
  const int r0 = blockIdx.y * 64;
  const int c0 = blockIdx.x * 64;
  const int tid = threadIdx.x;
  const float* ep = eS + (size_t)b * EPLN;

  __shared__ float ld[80][65];

  const int lx = tid & 63;
  const int wy = tid >> 6;
  const int mbase = 240 - c0 - (r0 >> 2);
  #pragma unroll
  for (int k = 0; k < 20; ++k) {
    const int p = wy + 4 * k;
    ld[p][lx] = ep[(size_t)(mbase + p) * 256 + r0 + lx];
  }
  __syncthreads();
  #pragma unroll
  for (int k = 0; k < 16; ++k) {
    const int rr = wy + 4 * k;
    aln[(size_t)b * NN * MM + (size_t)(r0 + rr) * MM + c0 + lx] =
        ld[78 - lx - (rr >> 2)][rr];
  }
}

// ---------------- launcher ----------------
extern "C" void kernel_launch(void* const* d_in, const int* in_sizes, int n_in,
                              void* d_out, int out_size, void* d_ws, size_t ws_size,
                              hipStream_t stream) {
  const float* zx = (const float*)d_in[0];
  const float* zy = (const float*)d_in[1];
  const float* gx = (const float*)d_in[2];
  const float* gy = (const float*)d_in[3];

  float* out   = (float*)d_out;
  float* aln   = out;                              // [B][N][M]
  float* theta = out + (size_t)BB * NN * MM;       // [B][N][M]
  float* Amat  = out + (size_t)2 * BB * NN * MM;   // [B][N][M]

  float* ws  = (float*)d_ws;
  float* thS = ws;                                   // [B][321][256] f32
  float* aS  = ws + (size_t)BB * SPLN;               // [B][321][256] f32
  u32x4_t* qS = (u32x4_t*)(ws + (size_t)2 * BB * SPLN);  // [B][321][64] u32x4
  float* eS = ws + (size_t)3 * BB * SPLN;            // [B][320][256] f32

  gemm_mfma<<<dim3(4, 4, 64), 256, 0, stream>>>(zx, zy, gx, gy,
                                                theta, Amat, thS, aS);
  nw_wave<<<BB, 64, 0, stream>>>(thS, aS, qS, eS);
  untwist<<<dim3(4, 4, BB), 256, 0, stream>>>(eS, aln);
}

// Round 20
// 157.829 us; speedup vs baseline: 1.7319x; 1.0221x over previous
//
#include <hip/hip_runtime.h>
#include <hip/hip_bf16.h>
#include <hip/hip_fp16.h>
#include <cstdint>
#include <cstddef>
#include <type_traits>

#define BB 32
#define NN 256
#define MM 256
#define DD 512
#define NEGF (-1e9f)
#define LOG2E 1.4426950408889634f
#define SPLN 82176   // 321*256 floats: th/a skew planes per batch
#define QPLN 82176   // 321*64 u32x4 in 4B words per batch
#define EPLNW 40960  // 320*128 u32 (=320 planes x 256 bf16) per batch

typedef __fp16 h2 __attribute__((ext_vector_type(2)));
typedef float f32x4_t __attribute__((ext_vector_type(4)));
typedef unsigned int u32x4_t __attribute__((ext_vector_type(4)));
typedef short s16x8 __attribute__((ext_vector_type(8)));

__device__ __forceinline__ uint32_t pack_q(float a, float b) {
  h2 r = __builtin_amdgcn_cvt_pkrtz(a, b);
  return __builtin_bit_cast(uint32_t, r);
}
__device__ __forceinline__ float2 unpack_q(uint32_t u) {
  h2 r = __builtin_bit_cast(h2, u);
  return make_float2((float)r.x, (float)r.y);
}
__device__ __forceinline__ uint32_t pkbf(float lo, float hi) {  // 2xf32 -> 2xbf16
  uint32_t r;
  asm("v_cvt_pk_bf16_f32 %0, %1, %2" : "=v"(r) : "v"(lo), "v"(hi));
  return r;
}
__device__ __forceinline__ float bf2f(uint16_t u) {
  return __builtin_bit_cast(float, (uint32_t)u << 16);
}
__device__ __forceinline__ float softplus_f(float x) {
  return fmaxf(x, 0.f) + __logf(1.f + __expf(-fabsf(x)));
}
__device__ __forceinline__ float logsig_f(float x) {
  return fminf(x, 0.f) - __logf(1.f + __expf(-fabsf(x)));
}
__device__ __forceinline__ short f2bf(float f) {   // RNE f32 -> bf16 bits
  uint32_t u = __builtin_bit_cast(uint32_t, f);
  u += 0x7FFFu + ((u >> 16) & 1u);
  return (short)(u >> 16);
}

#define WAITV(N) do { \
  asm volatile("s_waitcnt vmcnt(" #N ")" ::: "memory"); \
  __builtin_amdgcn_sched_barrier(0); \
} while (0)

#define DRAIN() do { \
  asm volatile("s_waitcnt vmcnt(0) lgkmcnt(0)" ::: "memory"); \
  __builtin_amdgcn_sched_barrier(0); \
} while (0)

#define SBAR() __builtin_amdgcn_sched_barrier(0)

// ---------- bf16-MFMA GEMM + activation + skew side store (both ops) -------
__global__ __launch_bounds__(256) void gemm_mfma(const float* __restrict__ ZX,
                                                 const float* __restrict__ ZY,
                                                 const float* __restrict__ GX,
                                                 const float* __restrict__ GY,
                                                 float* __restrict__ theta,
                                                 float* __restrict__ Amat,
                                                 float* __restrict__ thS,
                                                 float* __restrict__ aS) {
  const int z  = blockIdx.z;
  const int b  = z & 31;
  const int op = z >> 5;
  const int ty = blockIdx.y;
  const int tx = blockIdx.x;
  const float* Xb = (op ? GX : ZX) + (size_t)b * NN * DD;
  const float* Yb = (op ? GY : ZY) + (size_t)b * MM * DD;
  float* outb = (op ? Amat : theta) + (size_t)b * NN * MM;
  float* skb  = (op ? aS : thS) + (size_t)b * SPLN;

  __shared__ short xs[64][40];
  __shared__ short ys[64][40];

  const int tid = threadIdx.x;
  const int l   = tid & 63;
  const int w   = tid >> 6;
  const int r0  = (w >> 1) * 32;
  const int c0  = (w & 1) * 32;
  const int srow = tid >> 2;
  const int scg  = (tid & 3) * 8;

  f32x4_t acc[2][2];
  #pragma unroll
  for (int i = 0; i < 2; ++i)
    #pragma unroll
    for (int j = 0; j < 2; ++j) acc[i][j] = f32x4_t{0.f, 0.f, 0.f, 0.f};

  const int lr = l & 15;
  const int kof = (l >> 4) * 8;

  for (int ks = 0; ks < 16; ++ks) {
    const int k0 = ks * 32;
    const float4 xv0 = *(const float4*)(Xb + (size_t)(ty * 64 + srow) * DD + k0 + scg);
    const float4 xv1 = *(const float4*)(Xb + (size_t)(ty * 64 + srow) * DD + k0 + scg + 4);
    const float4 yv0 = *(const float4*)(Yb + (size_t)(tx * 64 + srow) * DD + k0 + scg);
    const float4 yv1 = *(const float4*)(Yb + (size_t)(tx * 64 + srow) * DD + k0 + scg + 4);
    __syncthreads();
    s16x8 xp, yp;
    xp[0] = f2bf(xv0.x); xp[1] = f2bf(xv0.y); xp[2] = f2bf(xv0.z); xp[3] = f2bf(xv0.w);
    xp[4] = f2bf(xv1.x); xp[5] = f2bf(xv1.y); xp[6] = f2bf(xv1.z); xp[7] = f2bf(xv1.w);
    yp[0] = f2bf(yv0.x); yp[1] = f2bf(yv0.y); yp[2] = f2bf(yv0.z); yp[3] = f2bf(yv0.w);
    yp[4] = f2bf(yv1.x); yp[5] = f2bf(yv1.y); yp[6] = f2bf(yv1.z); yp[7] = f2bf(yv1.w);
    *(s16x8*)&xs[srow][scg] = xp;
    *(s16x8*)&ys[srow][scg] = yp;
    __syncthreads();
    const s16x8 a0 = *(const s16x8*)&xs[r0 + lr][kof];
    const s16x8 a1 = *(const s16x8*)&xs[r0 + 16 + lr][kof];
    const s16x8 b0 = *(const s16x8*)&ys[c0 + lr][kof];
    const s16x8 b1 = *(const s16x8*)&ys[c0 + 16 + lr][kof];
    acc[0][0] = __builtin_amdgcn_mfma_f32_16x16x32_bf16(a0, b0, acc[0][0], 0, 0, 0);
    acc[0][1] = __builtin_amdgcn_mfma_f32_16x16x32_bf16(a0, b1, acc[0][1], 0, 0, 0);
    acc[1][0] = __builtin_amdgcn_mfma_f32_16x16x32_bf16(a1, b0, acc[1][0], 0, 0, 0);
    acc[1][1] = __builtin_amdgcn_mfma_f32_16x16x32_bf16(a1, b1, acc[1][1], 0, 0, 0);
  }

  #pragma unroll
  for (int i = 0; i < 2; ++i) {
    #pragma unroll
    for (int j = 0; j < 2; ++j) {
      const int Rb = ty * 64 + r0 + i * 16 + (l >> 4) * 4;  // base row, Rb%4==0
      const int C  = tx * 64 + c0 + j * 16 + (l & 15);
      float4 av;
      #pragma unroll
      for (int r = 0; r < 4; ++r) {
        const float v = acc[i][j][r];
        ((float*)&av)[r] = (op == 0) ? softplus_f(v) : logsig_f(v);
      }
      #pragma unroll
      for (int r = 0; r < 4; ++r)
        outb[(size_t)(Rb + r) * MM + C] = ((float*)&av)[r];
      float4 sv;
      #pragma unroll
      for (int r = 0; r < 4; ++r) ((float*)&sv)[r] = ((float*)&av)[r] * LOG2E;
      *(float4*)&skb[(size_t)(C + 1 + (Rb >> 2)) * 256 + Rb] = sv;
    }
  }
}

// -------- wave-synchronous soft-NW, skewed, DS-pipelined, region-split -----
__global__ __launch_bounds__(64, 1) void nw_wave(const float* __restrict__ thSA,
                                                 const float* __restrict__ aSA,
                                                 u32x4_t* __restrict__ qSA,
                                                 uint32_t* __restrict__ eSA) {
  const int b = blockIdx.x;
  const int t = threadIdx.x;
  const float* thS = thSA + (size_t)b * SPLN;
  const float* aS  = aSA  + (size_t)b * SPLN;
  u32x4_t* qS = qSA + (size_t)b * (QPLN / 4);
  uint32_t* eU = eSA + (size_t)b * EPLNW;

  __shared__ f32x4_t stg[24][64];

  // ================= forward =================
  float vp[4];
  #pragma unroll
  for (int k = 0; k < 4; ++k) vp[k] = NEGF;
  float vu_sh = NEGF, vd_sh = NEGF;

  auto fstage = [&](int rbase, int mlo) {
    #pragma unroll
    for (int q = 0; q < 4; ++q) {
      int m = mlo + q; m = m < 1 ? 1 : (m > 320 ? 320 : m);
      __builtin_amdgcn_global_load_lds((const void*)(thS + (size_t)m * 256 + 4 * t),
                                       (void*)&stg[rbase + q][0], 16, 0, 0);
      __builtin_amdgcn_global_load_lds((const void*)(aS + (size_t)m * 256 + 4 * t),
                                       (void*)&stg[rbase + 4 + q][0], 16, 0, 0);
    }
  };

  fstage(0, 1); fstage(8, 5); fstage(16, 9);

  auto fwd_seg = [&](const int h, const auto fullc) {
    constexpr bool FULL = decltype(fullc)::value;
    const int m0 = 1 + 4 * h;
    const int R = (h % 3) * 8;
    if (h == 0)      WAITV(16);
    else if (h == 1) WAITV(20);
    else             WAITV(24);
    u32x4_t* qseg = qS + (size_t)m0 * 64 + t;   // per-segment base; u*1KB imm
    f32x4_t thc = stg[R][t], ac = stg[R + 4][t];
    f32x4_t thn, an;
    #pragma unroll
    for (int u = 0; u < 4; ++u) {
      if (u < 3) { thn = stg[R + u + 1][t]; an = stg[R + 4 + u + 1][t]; }
      SBAR();
      const int m = m0 + u;
      float vu_in = vu_sh, vd_in = vd_sh;
      if (t == 0) { vu_in = NEGF; vd_in = (m == 1) ? 0.f : NEGF; }
      bool actv = true;
      if constexpr (!FULL) {
        const int j = m - t;
        actv = (j >= 1) && (j <= 256);
      }
      float vn[4], e0v[4], e2v[4], rzv[4];
      #pragma unroll
      for (int k = 0; k < 4; ++k) {
        const float vu  = (k == 0) ? vu_in : vn[k - 1];
        const float vdk = (k == 0) ? vd_in : vp[k - 1];
        const float x0 = ac[k] + vu;
        const float x2 = ac[k] + vp[k];
        const float mx = fmaxf(fmaxf(x0, vdk), x2);   // v_max3
        const float e0 = __builtin_amdgcn_exp2f(x0 - mx);
        const float e1 = __builtin_amdgcn_exp2f(vdk - mx);
        const float e2 = __builtin_amdgcn_exp2f(x2 - mx);
        const float Z  = e0 + e1 + e2;
        rzv[k] = __builtin_amdgcn_rcpf(Z);
        const float v  = thc[k] + mx + __builtin_amdgcn_logf(Z);  // log2
        vn[k] = FULL ? v : (actv ? v : vp[k]);
        e0v[k] = e0; e2v[k] = e2;
      }
      const float nsh = __shfl_up(vn[3], 1);
      uint32_t pk[4];
      #pragma unroll
      for (int k = 0; k < 4; ++k)
        pk[k] = pack_q(e0v[k] * rzv[k], e2v[k] * rzv[k]);  // (q1,q3)
      qseg[(size_t)u * 64] = u32x4_t{pk[0], pk[1], pk[2], pk[3]};
      vd_sh = vu_sh; vu_sh = nsh;
      #pragma unroll
      for (int k = 0; k < 4; ++k) vp[k] = vn[k];
      if (u < 3) { thc = thn; ac = an; }
    }
    fstage(R, m0 + 12);
  };

  for (int h = 0; h < 16; ++h)  fwd_seg(h, std::integral_constant<bool, false>{});
  for (int h = 16; h < 64; ++h) fwd_seg(h, std::integral_constant<bool, true>{});
  for (int h = 64; h < 80; ++h) fwd_seg(h, std::integral_constant<bool, false>{});

  DRAIN();  // qS RAW boundary (fwd stores -> bwd staged reads)

  // ================= backward =================
  float ep[4] = {0.f, 0.f, 0.f, 0.f};
  float sh_e1 = 0.f, sh_e2 = 0.f;
  uint32_t sh_q1 = 0u, sh_q2 = 0u;
  u32x4_t qm1 = u32x4_t{0u, 0u, 0u, 0u};
  const u32x4_t QONE = u32x4_t{0x3C00u, 0x3C00u, 0x3C00u, 0x3C00u};

  auto bstage = [&](int rbase, int Phi) {
    #pragma unroll
    for (int u = 0; u < 4; ++u) {
      int P = Phi - u; P = P < 0 ? 0 : (P > 320 ? 320 : P);
      __builtin_amdgcn_global_load_lds((const void*)(qS + (size_t)P * 64 + t),
                                       (void*)&stg[rbase + u][0], 16, 0, 0);
    }
  };

  bstage(0, 319); bstage(4, 315); bstage(8, 311);

  auto bwd_seg = [&](const int n, const auto fullc) {
    constexpr bool FULL = decltype(fullc)::value;
    const int R = (n % 3) * 4;
    if (n == 0)      WAITV(8);
    else if (n == 1) WAITV(12);
    else             WAITV(16);
    uint32_t* eseg = eU + (size_t)(4 * n) * 128 + 2 * t;  // u*512B imm offsets
    u32x4_t cur = __builtin_bit_cast(u32x4_t, stg[R][t]);
    u32x4_t nxt;
    #pragma unroll
    for (int u = 0; u < 4; ++u) {
      if (u < 3) nxt = __builtin_bit_cast(u32x4_t, stg[R + u + 1][t]);
      SBAR();
      const int mp = 4 * n + u;
      const int P  = 319 - mp;
      bool actv = true, jok = true;
      if constexpr (!FULL) {
        const int j = P - t;
        actv = (j >= 1) && (j <= 256);
        jok  = (j <= 255);
      }
      const u32x4_t qmm = FULL ? qm1 : (jok ? qm1 : QONE);
      const uint32_t sq1 = (t == 63) ? 0u : sh_q1;
      const uint32_t sq2 = (t == 63 || !jok) ? 0x3C00u : sh_q2;
      float en[4];
      #pragma unroll
      for (int kk = 0; kk < 4; ++kk) {
        const int k = 3 - kk;
        const uint32_t uA = (k < 3) ? cur[k + 1] : sq1;   // Q1 of (i+1, j)
        const uint32_t uB = (k < 3) ? qmm[k + 1] : sq2;   // Q of (i+1, j+1)
        const uint32_t uC = qmm[k];                       // Q3 of (i, j+1)
        const float2 fA = unpack_q(uA);
        const float2 fB = unpack_q(uB);
        const float2 fC = unpack_q(uC);
        const float q1u = fA.x;
        const float q2d = 1.f - fB.x - fB.y;
        const float q3l = fC.y;
        const float eu = (k < 3) ? en[k + 1] : sh_e1;
        const float ed = (k < 3) ? ep[k + 1] : sh_e2;
        const float el = ep[k];
        float E = q1u * eu + q2d * ed + q3l * el;
        if constexpr (!FULL) {
          if (n == 0 && u == 0 && k == 3) E = (t == 63) ? 1.f : E;  // seed
        }
        en[k] = FULL ? E : (actv ? E : 0.f);
      }
      const float ne = __shfl_down(en[0], 1);
      const uint32_t nq = (uint32_t)__shfl_down((int)cur[0], 1);
      *(uint2*)(eseg + (size_t)u * 128) =
          make_uint2(pkbf(en[0], en[1]), pkbf(en[2], en[3]));
      sh_e2 = sh_e1; sh_e1 = ne;
      sh_q2 = sh_q1; sh_q1 = nq;
      ep[0] = en[0]; ep[1] = en[1]; ep[2] = en[2]; ep[3] = en[3];
      qm1 = cur;
      if (u < 3) cur = nxt;
    }
    bstage(R, 307 - 4 * n);
  };

  for (int n = 0; n < 16; ++n)  bwd_seg(n, std::integral_constant<bool, false>{});
  for (int n = 16; n < 64; ++n) bwd_seg(n, std::integral_constant<bool, true>{});
  for (int n = 64; n < 80; ++n) bwd_seg(n, std::integral_constant<bool, false>{});
}

// -------- bf16 skew-layout E -> row-major f32 aln ---------------------------
// aln[r][c] = eS[318 - c - (r>>2)][r]
__global__ __launch_bounds__(256) void untwist(const uint32_t* __restrict__ eSu,
                                               float* __restrict__ aln) {
  const int b  = blockIdx.z;
  const int r0 = blockIdx.y * 64;
  const int c0 = blockIdx.x * 64;
  const int tid = threadIdx.x;
  const uint16_t* epb = (const uint16_t*)(eSu + (size_t)b * EPLNW);

  __shared__ float ld[80][65];

  const int mbase = 240 - c0 - (r0 >> 2);
  {
    const int c2 = (tid & 31) * 2;   // column pair
    const int r8 = tid >> 5;         // 0..7
    #pragma unroll
    for (int k = 0; k < 10; ++k) {
      const int p = r8 + 8 * k;      // 0..79
      const ushort2 v = *(const ushort2*)&epb[(size_t)(mbase + p) * 256 + r0 + c2];
      ld[p][c2]     = bf2f(v.x);
      ld[p][c2 + 1] = bf2f(v.y);
    }
  }
  __syncthreads();
  const int lx = tid & 63;
  const int wy = tid >> 6;
  #pragma unroll
  for (int k = 0; k < 16; ++k) {
    const int rr = wy + 4 * k;
    aln[(size_t)b * NN * MM + (size_t)(r0 + rr) * MM + c0 + lx] =
        ld[78 - lx - (rr >> 2)][rr];
  }
}

// ---------------- launcher ----------------
extern "C" void kernel_launch(void* const* d_in, const int* in_sizes, int n_in,
                              void* d_out, int out_size, void* d_ws, size_t ws_size,
                              hipStream_t stream) {
  const float* zx = (const float*)d_in[0];
  const float* zy = (const float*)d_in[1];
  const float* gx = (const float*)d_in[2];
  const float* gy = (const float*)d_in[3];

  float* out   = (float*)d_out;
  float* aln   = out;                              // [B][N][M]
  float* theta = out + (size_t)BB * NN * MM;       // [B][N][M]
  float* Amat  = out + (size_t)2 * BB * NN * MM;   // [B][N][M]

  float* ws  = (float*)d_ws;
  float* thS = ws;                                   // [B][321][256] f32
  float* aS  = ws + (size_t)BB * SPLN;               // [B][321][256] f32
  u32x4_t* qS = (u32x4_t*)(ws + (size_t)2 * BB * SPLN);  // [B][321][64] u32x4
  uint32_t* eS = (uint32_t*)(ws + (size_t)2 * BB * SPLN) + (size_t)BB * QPLN;
                                                     // [B][320][128] u32 (bf16x2)

  gemm_mfma<<<dim3(4, 4, 64), 256, 0, stream>>>(zx, zy, gx, gy,
                                                theta, Amat, thS, aS);
  nw_wave<<<BB, 64, 0, stream>>>(thS, aS, qS, eS);
  untwist<<<dim3(4, 4, BB), 256, 0, stream>>>(eS, aln);
}

// Round 21
// 155.595 us; speedup vs baseline: 1.7568x; 1.0144x over previous
//
#include <hip/hip_runtime.h>
#include <hip/hip_bf16.h>
#include <hip/hip_fp16.h>
#include <cstdint>
#include <cstddef>
#include <type_traits>

#define BB 32
#define NN 256
#define MM 256
#define DD 512
#define NEGF (-1e9f)
#define LOG2E 1.4426950408889634f
#define SPLN 82176   // 321*256 floats: th/a skew planes per batch
#define QPLN 82176   // 321*64 u32x4 in 4B words per batch
#define EPLNW 40960  // 320*128 u32 (=320 planes x 256 bf16) per batch

typedef __fp16 h2 __attribute__((ext_vector_type(2)));
typedef float f32x4_t __attribute__((ext_vector_type(4)));
typedef unsigned int u32x4_t __attribute__((ext_vector_type(4)));
typedef short s16x8 __attribute__((ext_vector_type(8)));

__device__ __forceinline__ uint32_t pack_q(float a, float b) {
  h2 r = __builtin_amdgcn_cvt_pkrtz(a, b);
  return __builtin_bit_cast(uint32_t, r);
}
__device__ __forceinline__ float2 unpack_q(uint32_t u) {
  h2 r = __builtin_bit_cast(h2, u);
  return make_float2((float)r.x, (float)r.y);
}
__device__ __forceinline__ uint32_t pkbf(float lo, float hi) {  // 2xf32 -> 2xbf16
  uint32_t r;
  asm("v_cvt_pk_bf16_f32 %0, %1, %2" : "=v"(r) : "v"(lo), "v"(hi));
  return r;
}
__device__ __forceinline__ float bf2f(uint16_t u) {
  return __builtin_bit_cast(float, (uint32_t)u << 16);
}
__device__ __forceinline__ float softplus_f(float x) {
  return fmaxf(x, 0.f) + __logf(1.f + __expf(-fabsf(x)));
}
__device__ __forceinline__ float logsig_f(float x) {
  return fminf(x, 0.f) - __logf(1.f + __expf(-fabsf(x)));
}
__device__ __forceinline__ short f2bf(float f) {   // RNE f32 -> bf16 bits
  uint32_t u = __builtin_bit_cast(uint32_t, f);
  u += 0x7FFFu + ((u >> 16) & 1u);
  return (short)(u >> 16);
}

#define WAITV(N) do { \
  asm volatile("s_waitcnt vmcnt(" #N ")" ::: "memory"); \
  __builtin_amdgcn_sched_barrier(0); \
} while (0)

#define DRAIN() do { \
  asm volatile("s_waitcnt vmcnt(0) lgkmcnt(0)" ::: "memory"); \
  __builtin_amdgcn_sched_barrier(0); \
} while (0)

#define SBAR() __builtin_amdgcn_sched_barrier(0)

// ---------- bf16-MFMA GEMM + activation + skew side store (both ops) -------
__global__ __launch_bounds__(256) void gemm_mfma(const float* __restrict__ ZX,
                                                 const float* __restrict__ ZY,
                                                 const float* __restrict__ GX,
                                                 const float* __restrict__ GY,
                                                 float* __restrict__ theta,
                                                 float* __restrict__ Amat,
                                                 float* __restrict__ thS,
                                                 float* __restrict__ aS) {
  const int z  = blockIdx.z;
  const int b  = z & 31;
  const int op = z >> 5;
  const int ty = blockIdx.y;
  const int tx = blockIdx.x;
  const float* Xb = (op ? GX : ZX) + (size_t)b * NN * DD;
  const float* Yb = (op ? GY : ZY) + (size_t)b * MM * DD;
  float* outb = (op ? Amat : theta) + (size_t)b * NN * MM;
  float* skb  = (op ? aS : thS) + (size_t)b * SPLN;

  __shared__ short xs[64][40];
  __shared__ short ys[64][40];

  const int tid = threadIdx.x;
  const int l   = tid & 63;
  const int w   = tid >> 6;
  const int r0  = (w >> 1) * 32;
  const int c0  = (w & 1) * 32;
  const int srow = tid >> 2;
  const int scg  = (tid & 3) * 8;

  f32x4_t acc[2][2];
  #pragma unroll
  for (int i = 0; i < 2; ++i)
    #pragma unroll
    for (int j = 0; j < 2; ++j) acc[i][j] = f32x4_t{0.f, 0.f, 0.f, 0.f};

  const int lr = l & 15;
  const int kof = (l >> 4) * 8;

  for (int ks = 0; ks < 16; ++ks) {
    const int k0 = ks * 32;
    const float4 xv0 = *(const float4*)(Xb + (size_t)(ty * 64 + srow) * DD + k0 + scg);
    const float4 xv1 = *(const float4*)(Xb + (size_t)(ty * 64 + srow) * DD + k0 + scg + 4);
    const float4 yv0 = *(const float4*)(Yb + (size_t)(tx * 64 + srow) * DD + k0 + scg);
    const float4 yv1 = *(const float4*)(Yb + (size_t)(tx * 64 + srow) * DD + k0 + scg + 4);
    __syncthreads();
    s16x8 xp, yp;
    xp[0] = f2bf(xv0.x); xp[1] = f2bf(xv0.y); xp[2] = f2bf(xv0.z); xp[3] = f2bf(xv0.w);
    xp[4] = f2bf(xv1.x); xp[5] = f2bf(xv1.y); xp[6] = f2bf(xv1.z); xp[7] = f2bf(xv1.w);
    yp[0] = f2bf(yv0.x); yp[1] = f2bf(yv0.y); yp[2] = f2bf(yv0.z); yp[3] = f2bf(yv0.w);
    yp[4] = f2bf(yv1.x); yp[5] = f2bf(yv1.y); yp[6] = f2bf(yv1.z); yp[7] = f2bf(yv1.w);
    *(s16x8*)&xs[srow][scg] = xp;
    *(s16x8*)&ys[srow][scg] = yp;
    __syncthreads();
    const s16x8 a0 = *(const s16x8*)&xs[r0 + lr][kof];
    const s16x8 a1 = *(const s16x8*)&xs[r0 + 16 + lr][kof];
    const s16x8 b0 = *(const s16x8*)&ys[c0 + lr][kof];
    const s16x8 b1 = *(const s16x8*)&ys[c0 + 16 + lr][kof];
    acc[0][0] = __builtin_amdgcn_mfma_f32_16x16x32_bf16(a0, b0, acc[0][0], 0, 0, 0);
    acc[0][1] = __builtin_amdgcn_mfma_f32_16x16x32_bf16(a0, b1, acc[0][1], 0, 0, 0);
    acc[1][0] = __builtin_amdgcn_mfma_f32_16x16x32_bf16(a1, b0, acc[1][0], 0, 0, 0);
    acc[1][1] = __builtin_amdgcn_mfma_f32_16x16x32_bf16(a1, b1, acc[1][1], 0, 0, 0);
  }

  #pragma unroll
  for (int i = 0; i < 2; ++i) {
    #pragma unroll
    for (int j = 0; j < 2; ++j) {
      const int Rb = ty * 64 + r0 + i * 16 + (l >> 4) * 4;  // base row, Rb%4==0
      const int C  = tx * 64 + c0 + j * 16 + (l & 15);
      float4 av;
      #pragma unroll
      for (int r = 0; r < 4; ++r) {
        const float v = acc[i][j][r];
        ((float*)&av)[r] = (op == 0) ? softplus_f(v) : logsig_f(v);
      }
      #pragma unroll
      for (int r = 0; r < 4; ++r)
        outb[(size_t)(Rb + r) * MM + C] = ((float*)&av)[r];
      float4 sv;
      #pragma unroll
      for (int r = 0; r < 4; ++r) ((float*)&sv)[r] = ((float*)&av)[r] * LOG2E;
      *(float4*)&skb[(size_t)(C + 1 + (Rb >> 2)) * 256 + Rb] = sv;
    }
  }
}

// -------- wave-synchronous soft-NW, skewed, 8-plane segments ---------------
// One wave per batch; lane t owns grid rows 4t+1..4t+4, col j = m - t.
// 3 banks x 8 planes both passes; counted vmcnt; FULL-region templating.
__global__ __launch_bounds__(64, 1) void nw_wave(const float* __restrict__ thSA,
                                                 const float* __restrict__ aSA,
                                                 u32x4_t* __restrict__ qSA,
                                                 uint32_t* __restrict__ eSA) {
  const int b = blockIdx.x;
  const int t = threadIdx.x;
  const float* thS = thSA + (size_t)b * SPLN;
  const float* aS  = aSA  + (size_t)b * SPLN;
  u32x4_t* qS = qSA + (size_t)b * (QPLN / 4);
  uint32_t* eU = eSA + (size_t)b * EPLNW;

  __shared__ f32x4_t stg[48][64];  // fwd: 3 banks x 16 rows; bwd: 3 x 8 rows

  // ================= forward =================
  float vp[4];
  #pragma unroll
  for (int k = 0; k < 4; ++k) vp[k] = NEGF;
  float vu_sh = NEGF, vd_sh = NEGF;

  auto fstage8 = [&](int rbase, int mlo) {
    #pragma unroll
    for (int q = 0; q < 8; ++q) {
      int m = mlo + q; m = m < 1 ? 1 : (m > 320 ? 320 : m);
      __builtin_amdgcn_global_load_lds((const void*)(thS + (size_t)m * 256 + 4 * t),
                                       (void*)&stg[rbase + q][0], 16, 0, 0);
      __builtin_amdgcn_global_load_lds((const void*)(aS + (size_t)m * 256 + 4 * t),
                                       (void*)&stg[rbase + 8 + q][0], 16, 0, 0);
    }
  };

  fstage8(0, 1); fstage8(16, 9); fstage8(32, 17);

  auto fwd_seg = [&](const int h, const auto fullc) {
    constexpr bool FULL = decltype(fullc)::value;
    const int m0 = 1 + 8 * h;
    const int R = (h % 3) * 16;
    if (h == 0)      WAITV(32);
    else if (h == 1) WAITV(40);
    else             WAITV(48);
    u32x4_t* qseg = qS + (size_t)m0 * 64 + t;
    f32x4_t thc = stg[R][t], ac = stg[R + 8][t];
    f32x4_t thn, an;
    #pragma unroll
    for (int u = 0; u < 8; ++u) {
      if (u < 7) { thn = stg[R + u + 1][t]; an = stg[R + 8 + u + 1][t]; }
      SBAR();
      const int m = m0 + u;
      float vu_in = vu_sh, vd_in = vd_sh;
      if (t == 0) { vu_in = NEGF; vd_in = (m == 1) ? 0.f : NEGF; }
      bool actv = true;
      if constexpr (!FULL) {
        const int j = m - t;
        actv = (j >= 1) && (j <= 256);
      }
      float vn[4], e0v[4], e2v[4], rzv[4];
      #pragma unroll
      for (int k = 0; k < 4; ++k) {
        const float vu  = (k == 0) ? vu_in : vn[k - 1];
        const float vdk = (k == 0) ? vd_in : vp[k - 1];
        const float x0 = ac[k] + vu;
        const float x2 = ac[k] + vp[k];
        const float mx = fmaxf(fmaxf(x0, vdk), x2);   // v_max3
        const float e0 = __builtin_amdgcn_exp2f(x0 - mx);
        const float e1 = __builtin_amdgcn_exp2f(vdk - mx);
        const float e2 = __builtin_amdgcn_exp2f(x2 - mx);
        const float Z  = e0 + e1 + e2;
        rzv[k] = __builtin_amdgcn_rcpf(Z);
        const float v  = thc[k] + mx + __builtin_amdgcn_logf(Z);  // log2
        vn[k] = FULL ? v : (actv ? v : vp[k]);
        e0v[k] = e0; e2v[k] = e2;
      }
      const float nsh = __shfl_up(vn[3], 1);
      uint32_t pk[4];
      #pragma unroll
      for (int k = 0; k < 4; ++k)
        pk[k] = pack_q(e0v[k] * rzv[k], e2v[k] * rzv[k]);  // (q1,q3)
      qseg[(size_t)u * 64] = u32x4_t{pk[0], pk[1], pk[2], pk[3]};
      vd_sh = vu_sh; vu_sh = nsh;
      #pragma unroll
      for (int k = 0; k < 4; ++k) vp[k] = vn[k];
      if (u < 7) { thc = thn; ac = an; }
    }
    fstage8(R, m0 + 24);
  };

  for (int h = 0; h < 8; ++h)   fwd_seg(h, std::integral_constant<bool, false>{});
  for (int h = 8; h < 32; ++h)  fwd_seg(h, std::integral_constant<bool, true>{});
  for (int h = 32; h < 40; ++h) fwd_seg(h, std::integral_constant<bool, false>{});

  DRAIN();  // qS RAW boundary (fwd stores -> bwd staged reads)

  // ================= backward =================
  float ep[4] = {0.f, 0.f, 0.f, 0.f};
  float sh_e1 = 0.f, sh_e2 = 0.f;
  uint32_t sh_q1 = 0u, sh_q2 = 0u;
  u32x4_t qm1 = u32x4_t{0u, 0u, 0u, 0u};
  const u32x4_t QONE = u32x4_t{0x3C00u, 0x3C00u, 0x3C00u, 0x3C00u};

  auto bstage8 = [&](int rbase, int Phi) {
    #pragma unroll
    for (int u = 0; u < 8; ++u) {
      int P = Phi - u; P = P < 0 ? 0 : (P > 320 ? 320 : P);
      __builtin_amdgcn_global_load_lds((const void*)(qS + (size_t)P * 64 + t),
                                       (void*)&stg[rbase + u][0], 16, 0, 0);
    }
  };

  bstage8(0, 319); bstage8(8, 311); bstage8(16, 303);

  auto bwd_seg = [&](const int n, const auto fullc) {
    constexpr bool FULL = decltype(fullc)::value;
    const int R = (n % 3) * 8;
    if (n == 0)      WAITV(16);
    else if (n == 1) WAITV(24);
    else             WAITV(32);
    uint32_t* eseg = eU + (size_t)(8 * n) * 128 + 2 * t;
    u32x4_t cur = __builtin_bit_cast(u32x4_t, stg[R][t]);
    u32x4_t nxt;
    #pragma unroll
    for (int u = 0; u < 8; ++u) {
      if (u < 7) nxt = __builtin_bit_cast(u32x4_t, stg[R + u + 1][t]);
      SBAR();
      const int mp = 8 * n + u;
      const int P  = 319 - mp;
      bool actv = true, jok = true;
      if constexpr (!FULL) {
        const int j = P - t;
        actv = (j >= 1) && (j <= 256);
        jok  = (j <= 255);
      }
      const u32x4_t qmm = FULL ? qm1 : (jok ? qm1 : QONE);
      const uint32_t sq1 = (t == 63) ? 0u : sh_q1;
      const uint32_t sq2 = (t == 63 || !jok) ? 0x3C00u : sh_q2;
      float en[4];
      #pragma unroll
      for (int kk = 0; kk < 4; ++kk) {
        const int k = 3 - kk;
        const uint32_t uA = (k < 3) ? cur[k + 1] : sq1;   // Q1 of (i+1, j)
        const uint32_t uB = (k < 3) ? qmm[k + 1] : sq2;   // Q of (i+1, j+1)
        const uint32_t uC = qmm[k];                       // Q3 of (i, j+1)
        const float2 fA = unpack_q(uA);
        const float2 fB = unpack_q(uB);
        const float2 fC = unpack_q(uC);
        const float q1u = fA.x;
        const float q2d = 1.f - fB.x - fB.y;
        const float q3l = fC.y;
        const float eu = (k < 3) ? en[k + 1] : sh_e1;
        const float ed = (k < 3) ? ep[k + 1] : sh_e2;
        const float el = ep[k];
        float E = q1u * eu + q2d * ed + q3l * el;
        if constexpr (!FULL) {
          if (n == 0 && u == 0 && k == 3) E = (t == 63) ? 1.f : E;  // seed
        }
        en[k] = FULL ? E : (actv ? E : 0.f);
      }
      const float ne = __shfl_down(en[0], 1);
      const uint32_t nq = (uint32_t)__shfl_down((int)cur[0], 1);
      *(uint2*)(eseg + (size_t)u * 128) =
          make_uint2(pkbf(en[0], en[1]), pkbf(en[2], en[3]));
      sh_e2 = sh_e1; sh_e1 = ne;
      sh_q2 = sh_q1; sh_q1 = nq;
      ep[0] = en[0]; ep[1] = en[1]; ep[2] = en[2]; ep[3] = en[3];
      qm1 = cur;
      if (u < 7) cur = nxt;
    }
    bstage8(R, 295 - 8 * n);
  };

  for (int n = 0; n < 8; ++n)   bwd_seg(n, std::integral_constant<bool, false>{});
  for (int n = 8; n < 32; ++n)  bwd_seg(n, std::integral_constant<bool, true>{});
  for (int n = 32; n < 40; ++n) bwd_seg(n, std::integral_constant<bool, false>{});
}

// -------- bf16 skew-layout E -> row-major f32 aln ---------------------------
// aln[r][c] = eS[318 - c - (r>>2)][r]
__global__ __launch_bounds__(256) void untwist(const uint32_t* __restrict__ eSu,
                                               float* __restrict__ aln) {
  const int b  = blockIdx.z;
  const int r0 = blockIdx.y * 64;
  const int c0 = blockIdx.x * 64;
  const int tid = threadIdx.x;
  const uint16_t* epb = (const uint16_t*)(eSu + (size_t)b * EPLNW);

  __shared__ float ld[80][65];

  const int mbase = 240 - c0 - (r0 >> 2);
  {
    const int c2 = (tid & 31) * 2;   // column pair
    const int r8 = tid >> 5;         // 0..7
    #pragma unroll
    for (int k = 0; k < 10; ++k) {
      const int p = r8 + 8 * k;      // 0..79
      const ushort2 v = *(const ushort2*)&epb[(size_t)(mbase + p) * 256 + r0 + c2];
      ld[p][c2]     = bf2f(v.x);
      ld[p][c2 + 1] = bf2f(v.y);
    }
  }
  __syncthreads();
  const int lx = tid & 63;
  const int wy = tid >> 6;
  #pragma unroll
  for (int k = 0; k < 16; ++k) {
    const int rr = wy + 4 * k;
    aln[(size_t)b * NN * MM + (size_t)(r0 + rr) * MM + c0 + lx] =
        ld[78 - lx - (rr >> 2)][rr];
  }
}

// ---------------- launcher ----------------
extern "C" void kernel_launch(void* const* d_in, const int* in_sizes, int n_in,
                              void* d_out, int out_size, void* d_ws, size_t ws_size,
                              hipStream_t stream) {
  const float* zx = (const float*)d_in[0];
  const float* zy = (const float*)d_in[1];
  const float* gx = (const float*)d_in[2];
  const float* gy = (const float*)d_in[3];

  float* out   = (float*)d_out;
  float* aln   = out;                              // [B][N][M]
  float* theta = out + (size_t)BB * NN * MM;       // [B][N][M]
  float* Amat  = out + (size_t)2 * BB * NN * MM;   // [B][N][M]

  float* ws  = (float*)d_ws;
  float* thS = ws;                                   // [B][321][256] f32
  float* aS  = ws + (size_t)BB * SPLN;               // [B][321][256] f32
  u32x4_t* qS = (u32x4_t*)(ws + (size_t)2 * BB * SPLN);  // [B][321][64] u32x4
  uint32_t* eS = (uint32_t*)(ws + (size_t)2 * BB * SPLN) + (size_t)BB * QPLN;
                                                     // [B][320][128] u32 (bf16x2)

  gemm_mfma<<<dim3(4, 4, 64), 256, 0, stream>>>(zx, zy, gx, gy,
                                                theta, Amat, thS, aS);
  nw_wave<<<BB, 64, 0, stream>>>(thS, aS, qS, eS);
  untwist<<<dim3(4, 4, BB), 256, 0, stream>>>(eS, aln);
}